// Round 9
// baseline (62.069 us; speedup 1.0000x reference)
//
#include <hip/hip_runtime.h>

typedef float f4 __attribute__((ext_vector_type(4)));
typedef float f32x4 __attribute__((ext_vector_type(4)));
typedef _Float16 f16x8 __attribute__((ext_vector_type(8)));
typedef _Float16 f16x4 __attribute__((ext_vector_type(4)));

// x-arena: 16 rows x 512B (256 f16). fb = feature*2.
__device__ __forceinline__ int XSW(int row, int fb) {
    return row * 512 + (fb ^ ((row & 7) << 4));
}
// h-arena: 16 rows x 1024B (512 f16). k = 16B chunk index (features 8k..8k+7).
__device__ __forceinline__ int HBY(int row, int k, int sub) {
    return row * 1024 + (((k ^ ((k >> 3) & 7) ^ (row & 7)) << 4) + sub);
}

// ---------- pre-pass: W -> MFMA fragment pages fp16 (unchanged, verified) ----------
// Page p = nt*KT+kt: 512 f16, lane l holds W[32kt+8*(l>>4)+j][16nt+(l&15)], j=0..7.
// Regions (f16 units): W1 @ 0 (32 pages), W2 @ 16384 (128), W3 @ 81920 (256).
__global__ __launch_bounds__(256) void prep_frags_all(
    const float* __restrict__ W1, const float* __restrict__ W2,
    const float* __restrict__ W3, _Float16* __restrict__ dst) {
    __shared__ float s[32 * 264];
    const int b = blockIdx.x, tid = threadIdx.x;
    const float* W; int N, kt, nh, KT; size_t off;
    if (b < 2)       { W = W1; N = 256; KT = 2; kt = b;            nh = 0;          off = 0; }
    else if (b < 10) { W = W2; N = 256; KT = 8; kt = b - 2;        nh = 0;          off = 16384; }
    else             { W = W3; N = 512; KT = 8; kt = (b - 10) >> 1; nh = (b - 10) & 1; off = 81920; }
    #pragma unroll
    for (int rep = 0; rep < 8; ++rep) {
        int fi = rep * 256 + tid;
        int row = fi >> 6, c4 = fi & 63;
        f4 v = *(const f4*)&W[(kt * 32 + row) * N + nh * 256 + c4 * 4];
        *(f4*)&s[row * 264 + c4 * 4] = v;
    }
    __syncthreads();
    const int wv = tid >> 6, l = tid & 63, lr = l & 15, lg = l >> 4;
    #pragma unroll
    for (int p = 0; p < 4; ++p) {
        int lnt = wv * 4 + p;
        f16x8 o;
        #pragma unroll
        for (int j = 0; j < 8; ++j)
            o[j] = (_Float16)s[(lg * 8 + j) * 264 + lnt * 16 + lr];
        int page = (nh * 16 + lnt) * KT + kt;
        *(f16x8*)&dst[off + (size_t)page * 512 + l * 8] = o;
    }
}

__device__ __forceinline__ float ftanh(float x) {
    float e = __expf(2.0f * x);
    return 1.0f - 2.0f / (e + 1.0f);
}
__device__ __forceinline__ float red8(float x) {   // sum over aligned 8-lane groups
    x += __shfl_xor(x, 1); x += __shfl_xor(x, 2); x += __shfl_xor(x, 4);
    return x;
}

// One wave per block; 16 batch rows per wave, fully private: NO barriers anywhere.
// All layers computed transposed: x^T = W^T x^T, with weight pages as A-operands
// (page bytes are simultaneously the B-frag of W and the A-frag of W^T).
// D-tile: lane l reg r = x^T[16nt+4*(l>>4)+r][batch l&15] = x[batch][feature].
__global__ __launch_bounds__(64, 2) void scl_wave(
    const float* __restrict__ cond, const float* __restrict__ act,
    const float* __restrict__ b1, const float* __restrict__ b2,
    const float* __restrict__ b3,
    const _Float16* __restrict__ wf,
    float* __restrict__ out)
{
    __shared__ char smem[16384];   // [0,8K) x-arena; [0,16K) h-arena (overlays x)

    const int l  = threadIdx.x;
    const int lr = l & 15, lg = l >> 4;
    const int rb = blockIdx.x * 16;
    const f16x8* wp = (const f16x8*)wf;   // page stride 64 f16x8

    // ---- prologue: act rows for the tail (2 passes), cond B-frags
    f4 av[2][2];
    #pragma unroll
    for (int p = 0; p < 2; ++p) {
        const float* ap = act + (rb + 8 * p + (l >> 3)) * 64 + (l & 7) * 8;
        av[p][0] = *(const f4*)ap;
        av[p][1] = *(const f4*)(ap + 4);
    }
    f16x8 bc[2];   // B-frag of cond^T: lane holds cond[rb+lr][32kt+8lg+j]
    {
        const float* crow = cond + (rb + lr) * 64 + lg * 8;
        #pragma unroll
        for (int kt = 0; kt < 2; ++kt) {
            f4 va = *(const f4*)(crow + kt * 32);
            f4 vb = *(const f4*)(crow + kt * 32 + 4);
            #pragma unroll
            for (int j = 0; j < 4; ++j) {
                bc[kt][j]     = (_Float16)va[j];
                bc[kt][4 + j] = (_Float16)vb[j];
            }
        }
    }

    // ---------------- layer 1: x1^T = W1^T cond^T  (16 nt-tiles, K=64)
    #pragma unroll 4
    for (int nt = 0; nt < 16; ++nt) {
        f4 bi = *(const f4*)&b1[nt * 16 + lg * 4];
        f32x4 acc = {bi[0], bi[1], bi[2], bi[3]};
        #pragma unroll
        for (int kt = 0; kt < 2; ++kt)
            acc = __builtin_amdgcn_mfma_f32_16x16x32_f16(wp[(nt * 2 + kt) * 64 + l], bc[kt], acc, 0, 0, 0);
        f16x4 hp;
        #pragma unroll
        for (int r = 0; r < 4; ++r) hp[r] = (_Float16)ftanh(acc[r]);
        // feature 16nt+4lg+r of batch row lr
        *(f16x4*)(smem + XSW(lr, (nt * 16 + lg * 4) * 2)) = hp;
    }

    // ---------------- layer 2: x2^T = W2^T x1^T  (16 nt, K=256)
    f16x8 xf[8];
    #pragma unroll
    for (int kt = 0; kt < 8; ++kt)
        xf[kt] = *(const f16x8*)(smem + XSW(lr, (kt * 32 + lg * 8) * 2));
    #pragma unroll 2
    for (int nt = 0; nt < 16; ++nt) {
        f4 bi = *(const f4*)&b2[nt * 16 + lg * 4];
        f32x4 acc = {bi[0], bi[1], bi[2], bi[3]};
        #pragma unroll
        for (int kt = 0; kt < 8; ++kt)
            acc = __builtin_amdgcn_mfma_f32_16x16x32_f16(wp[2048 + (nt * 8 + kt) * 64 + l], xf[kt], acc, 0, 0, 0);
        f16x4 hp;
        #pragma unroll
        for (int r = 0; r < 4; ++r) hp[r] = (_Float16)ftanh(acc[r]);
        *(f16x4*)(smem + XSW(lr, (nt * 16 + lg * 4) * 2)) = hp;   // overwrite with x2 (xf already read)
    }

    // ---------------- layer 3: h^T = W3^T x2^T + b3  (32 nt, K=256) -> h-arena
    f16x8 yf[8];
    #pragma unroll
    for (int kt = 0; kt < 8; ++kt)
        yf[kt] = *(const f16x8*)(smem + XSW(lr, (kt * 32 + lg * 8) * 2));
    #pragma unroll 2
    for (int nt = 0; nt < 32; ++nt) {
        f4 bi = *(const f4*)&b3[nt * 16 + lg * 4];
        f32x4 acc = {bi[0], bi[1], bi[2], bi[3]};
        #pragma unroll
        for (int kt = 0; kt < 8; ++kt)
            acc = __builtin_amdgcn_mfma_f32_16x16x32_f16(wp[10240 + (nt * 8 + kt) * 64 + l], yf[kt], acc, 0, 0, 0);
        f16x4 hp;
        #pragma unroll
        for (int r = 0; r < 4; ++r) hp[r] = (_Float16)acc[r];
        // features 16nt+4lg+{0..3} -> chunk k=2nt+(lg>>1), byte-sub 8*(lg&1)
        *(f16x4*)(smem + HBY(lr, 2 * nt + (lg >> 1), 8 * (lg & 1))) = hp;
    }

    // ---------------- Householder tail: 2 passes x (8 rows, 8 lanes/row, 8 n/lane)
    #pragma unroll
    for (int p = 0; p < 2; ++p) {
        const int c = l & 7, br = 8 * p + (l >> 3);
        f16x8 hv[8];
        #pragma unroll
        for (int j = 0; j < 8; ++j)
            hv[j] = *(const f16x8*)(smem + HBY(br, 8 * c + j, 0));
        float h[8][8];   // h[cc][j], column n = 8c+j
        #pragma unroll
        for (int cc = 0; cc < 8; ++cc)
            #pragma unroll
            for (int j = 0; j < 8; ++j)
                h[cc][j] = (float)hv[j][cc];
        float inv[8];
        #pragma unroll
        for (int cc = 0; cc < 8; ++cc) {
            float s = 0.0f;
            #pragma unroll
            for (int j = 0; j < 8; ++j) s += h[cc][j] * h[cc][j];
            inv[cc] = 2.0f / red8(s);
        }
        float u[8] = {av[p][0][0], av[p][0][1], av[p][0][2], av[p][0][3],
                      av[p][1][0], av[p][1][1], av[p][1][2], av[p][1][3]};
        #pragma unroll
        for (int cc = 7; cc >= 0; --cc) {            // a* = E^T Q0..Q7 a
            float d = 0.0f;
            #pragma unroll
            for (int j = 0; j < 8; ++j) d += h[cc][j] * u[j];
            float t = inv[cc] * red8(d);
            #pragma unroll
            for (int j = 0; j < 8; ++j) u[j] -= t * h[cc][j];
        }
        float wv[8];
        #pragma unroll
        for (int j = 0; j < 8; ++j) wv[j] = (c == 0) ? u[j] : 0.0f;   // E a*
        #pragma unroll
        for (int cc = 0; cc < 8; ++cc) {             // q = Q7..Q0 (E a*)
            float d = 0.0f;
            #pragma unroll
            for (int j = 0; j < 8; ++j) d += h[cc][j] * wv[j];
            float t = inv[cc] * red8(d);
            #pragma unroll
            for (int j = 0; j < 8; ++j) wv[j] -= t * h[cc][j];
        }
        float* op = out + (rb + br) * 64 + c * 8;
        f4 o0 = {wv[0], wv[1], wv[2], wv[3]};
        f4 o1 = {wv[4], wv[5], wv[6], wv[7]};
        *(f4*)op = o0;
        *(f4*)(op + 4) = o1;
    }
}

extern "C" void kernel_launch(void* const* d_in, const int* in_sizes, int n_in,
                              void* d_out, int out_size, void* d_ws, size_t ws_size,
                              hipStream_t stream) {
    const float* cond = (const float*)d_in[0];
    const float* act  = (const float*)d_in[1];
    const float* W1   = (const float*)d_in[2];
    const float* b1   = (const float*)d_in[3];
    const float* W2   = (const float*)d_in[4];
    const float* b2   = (const float*)d_in[5];
    const float* W3   = (const float*)d_in[6];
    const float* b3   = (const float*)d_in[7];
    float* outp = (float*)d_out;

    _Float16* wf = (_Float16*)d_ws;   // 425984 bytes
    prep_frags_all<<<dim3(26), dim3(256), 0, stream>>>(W1, W2, W3, wf);
    scl_wave<<<dim3(512), dim3(64), 0, stream>>>(cond, act, b1, b2, b3, wf, outp);
}

// Round 10
// 29.805 us; speedup vs baseline: 2.0825x; 2.0825x over previous
//
#include <hip/hip_runtime.h>

typedef float f4 __attribute__((ext_vector_type(4)));
typedef float f2 __attribute__((ext_vector_type(2)));
typedef float f32x4 __attribute__((ext_vector_type(4)));
typedef _Float16 f16x8 __attribute__((ext_vector_type(8)));

// x-arena element address: [16 rows][256+8 f16], row stride 528B,
// 16B chunks XOR-swizzled by row (breaks the 8-bank-group aliasing of
// strided b128 reads; write and read sides use the same map).
__device__ __forceinline__ int XA(int row, int col) {
    return row * 528 + ((((col >> 3) ^ (row & 7)) << 4) + ((col & 7) << 1));
}
// h-arena: 16 rows x 1056B, 16B-chunk swizzle (R8-proven).
#define HSWZ16(o) ((o) ^ (((o) >> 3) & 0x70))

// Barrier draining LDS ops only — outstanding GLOBAL loads stay in flight.
#define BARLG() asm volatile("s_waitcnt lgkmcnt(0)\n\ts_barrier" ::: "memory")

// ---------- pre-pass: W -> MFMA fragment pages fp16 (416 blocks, max parallel) ----------
// Page p = nt*KT+kt: 512 f16, lane l holds W[32kt+8*(l>>4)+j][16nt+(l&15)], j=0..7.
// Regions (f16 units): W1 @ 0 (32 pages), W2 @ 16384 (128), W3 @ 81920 (256).
__global__ __launch_bounds__(256) void prep_frags_all(
    const float* __restrict__ W1, const float* __restrict__ W2,
    const float* __restrict__ W3, _Float16* __restrict__ dst) {
    int p = blockIdx.x;                 // one page per 256-thread block
    int q = threadIdx.x & 3, l = (threadIdx.x >> 2) & 63;
    const float* W; int K, N, lp; size_t off;
    if (p < 32)       { W = W1; K = 64;  N = 256; lp = p;       off = 0; }
    else if (p < 160) { W = W2; K = 256; N = 256; lp = p - 32;  off = 16384; }
    else              { W = W3; K = 256; N = 512; lp = p - 160; off = 81920; }
    int KT = K >> 5;
    int kt = lp % KT, nt = lp / KT;
    int k = kt * 32 + ((l >> 4) << 3) + 2 * q;
    int n = nt * 16 + (l & 15);
    size_t base = off + (size_t)lp * 512 + l * 8 + 2 * q;
    dst[base]     = (_Float16)W[k * N + n];
    dst[base + 1] = (_Float16)W[(k + 1) * N + n];
}

__device__ __forceinline__ float ftanh(float x) {
    float e = __expf(2.0f * x);
    return 1.0f - 2.0f / (e + 1.0f);
}
__device__ __forceinline__ float red32(float x) {  // sum over 32-lane groups
    x += __shfl_xor(x, 1); x += __shfl_xor(x, 2);  x += __shfl_xor(x, 4);
    x += __shfl_xor(x, 8); x += __shfl_xor(x, 16);
    return x;
}

// M=16 rows/block, 512 threads (8 waves), 512 blocks.
// Target: 4 blocks/CU = 8 waves/SIMD (VGPR <= 64, LDS 16.9KB).
// Weight pages loaded in-loop; 8-wave TLP hides the L2 latency.
__global__ __launch_bounds__(512, 8) void scl_mfma(
    const float* __restrict__ cond, const float* __restrict__ act,
    const float* __restrict__ b1, const float* __restrict__ b2,
    const float* __restrict__ b3,
    const _Float16* __restrict__ wf,
    float* __restrict__ out)
{
    // LDS 16896 B:
    //   [0,8448)      x1 arena (XA layout)     (dead after L2 reads)
    //   [8448,16896)  x2 arena (XA layout)     (dead after L3 reads)
    //   [0,16896)     h: 16 rows x 1056B, swizzled (overlays x1+x2)
    __shared__ char smem[16896];

    const int tid = threadIdx.x;
    const int w   = tid >> 6;   // wave 0..7
    const int l   = tid & 63;
    const int lr  = l & 15;
    const int lg  = l >> 4;
    const int rb  = blockIdx.x * 16;
    const f16x8* wp = (const f16x8*)wf;   // page stride 64 (f16x8 units)

    // ---- prologue: tail act row, cond A-frags, bias scalars
    const int hrow = w * 2 + (l >> 5), hc = l & 31;
    f2 av = *(const f2*)&act[(rb + hrow) * 64 + 2 * hc];
    f16x8 a1[2];
    {
        const float* crow = cond + (rb + lr) * 64 + lg * 8;
        #pragma unroll
        for (int kt = 0; kt < 2; ++kt) {
            f4 va = *(const f4*)(crow + kt * 32);
            f4 vb = *(const f4*)(crow + kt * 32 + 4);
            #pragma unroll
            for (int j = 0; j < 4; ++j) {
                a1[kt][j]     = (_Float16)va[j];
                a1[kt][4 + j] = (_Float16)vb[j];
            }
        }
    }
    float b1v[2], b2v[2], b3v[4];
    #pragma unroll
    for (int n = 0; n < 2; ++n) {
        b1v[n] = b1[(2 * w + n) * 16 + lr];
        b2v[n] = b2[(2 * w + n) * 16 + lr];
    }
    #pragma unroll
    for (int n = 0; n < 4; ++n) b3v[n] = b3[(4 * w + n) * 16 + lr];

    // ---------------- layer 1: cond[16x64] @ W1 -> x1 (bias as C-init)
    #pragma unroll
    for (int n = 0; n < 2; ++n) {
        f32x4 acc = {b1v[n], b1v[n], b1v[n], b1v[n]};
        #pragma unroll
        for (int kt = 0; kt < 2; ++kt)
            acc = __builtin_amdgcn_mfma_f32_16x16x32_f16(
                a1[kt], wp[((2 * w + n) * 2 + kt) * 64 + l], acc, 0, 0, 0);
        #pragma unroll
        for (int r = 0; r < 4; ++r) {
            // C/D: col = l&15, row = (l>>4)*4 + r
            float v = ftanh(acc[r]);
            *(_Float16*)(smem + XA(lg * 4 + r, (2 * w + n) * 16 + lr)) = (_Float16)v;
        }
    }
    BARLG();

    // ---------------- layer 2: x1 @ W2 -> x2
    {
        f32x4 acc[2] = {{b2v[0], b2v[0], b2v[0], b2v[0]},
                        {b2v[1], b2v[1], b2v[1], b2v[1]}};
        #pragma unroll 2
        for (int kt = 0; kt < 8; ++kt) {
            f16x8 A = *(const f16x8*)(smem + XA(lr, kt * 32 + lg * 8));
            #pragma unroll
            for (int n = 0; n < 2; ++n)
                acc[n] = __builtin_amdgcn_mfma_f32_16x16x32_f16(
                    A, wp[2048 + ((2 * w + n) * 8 + kt) * 64 + l], acc[n], 0, 0, 0);
        }
        #pragma unroll
        for (int n = 0; n < 2; ++n)
            #pragma unroll
            for (int r = 0; r < 4; ++r) {
                float v = ftanh(acc[n][r]);
                *(_Float16*)(smem + 8448 + XA(lg * 4 + r, (2 * w + n) * 16 + lr)) = (_Float16)v;
            }
    }
    BARLG();

    // ---------------- layer 3: x2 @ W3 + b3 -> h (overlays x1+x2 after barrier)
    {
        f32x4 acc[4] = {{b3v[0], b3v[0], b3v[0], b3v[0]},
                        {b3v[1], b3v[1], b3v[1], b3v[1]},
                        {b3v[2], b3v[2], b3v[2], b3v[2]},
                        {b3v[3], b3v[3], b3v[3], b3v[3]}};
        #pragma unroll 1
        for (int kt = 0; kt < 8; ++kt) {
            f16x8 A = *(const f16x8*)(smem + 8448 + XA(lr, kt * 32 + lg * 8));
            #pragma unroll
            for (int n = 0; n < 4; ++n)
                acc[n] = __builtin_amdgcn_mfma_f32_16x16x32_f16(
                    A, wp[10240 + ((4 * w + n) * 8 + kt) * 64 + l], acc[n], 0, 0, 0);
        }
        BARLG();   // all x2 reads done block-wide before h overlays
        #pragma unroll
        for (int n = 0; n < 4; ++n) {
            int col = (4 * w + n) * 16 + lr;
            #pragma unroll
            for (int r = 0; r < 4; ++r)
                *(_Float16*)(smem + (lg * 4 + r) * 1056 + HSWZ16(col * 2)) =
                    (_Float16)acc[n][r];
        }
    }
    BARLG();

    // ---------------- Householder tail: 2 rows/wave, 32 lanes/row, 2 cols/lane.
    // Lane owns HH-columns n = {2hc, 2hc+1}; h[cc][j] = element (col 2hc+j, refl cc).
    {
        f16x8 hv[2];
        #pragma unroll
        for (int j = 0; j < 2; ++j)
            hv[j] = *(const f16x8*)(smem + hrow * 1056 + HSWZ16((2 * hc + j) * 16));
        float h[8][2];
        #pragma unroll
        for (int cc = 0; cc < 8; ++cc) {
            h[cc][0] = (float)hv[0][cc];
            h[cc][1] = (float)hv[1][cc];
        }
        float inv[8];
        #pragma unroll
        for (int cc = 0; cc < 8; ++cc) {
            float s = h[cc][0] * h[cc][0] + h[cc][1] * h[cc][1];
            inv[cc] = 2.0f / red32(s);
        }
        float u[2] = {av[0], av[1]};
        #pragma unroll
        for (int cc = 7; cc >= 0; --cc) {            // a* = E^T Q0..Q7 a
            float d = red32(h[cc][0] * u[0] + h[cc][1] * u[1]);
            float t = inv[cc] * d;
            u[0] -= t * h[cc][0];
            u[1] -= t * h[cc][1];
        }
        float wv[2];
        wv[0] = (hc < 4) ? u[0] : 0.0f;               // E a*  (cols 2hc,2hc+1 < 8)
        wv[1] = (hc < 4) ? u[1] : 0.0f;
        #pragma unroll
        for (int cc = 0; cc < 8; ++cc) {             // q = Q7..Q0 (E a*)
            float d = red32(h[cc][0] * wv[0] + h[cc][1] * wv[1]);
            float t = inv[cc] * d;
            wv[0] -= t * h[cc][0];
            wv[1] -= t * h[cc][1];
        }
        f2 o = {wv[0], wv[1]};
        *(f2*)&out[(rb + hrow) * 64 + 2 * hc] = o;
    }
}

extern "C" void kernel_launch(void* const* d_in, const int* in_sizes, int n_in,
                              void* d_out, int out_size, void* d_ws, size_t ws_size,
                              hipStream_t stream) {
    const float* cond = (const float*)d_in[0];
    const float* act  = (const float*)d_in[1];
    const float* W1   = (const float*)d_in[2];
    const float* b1   = (const float*)d_in[3];
    const float* W2   = (const float*)d_in[4];
    const float* b2   = (const float*)d_in[5];
    const float* W3   = (const float*)d_in[6];
    const float* b3   = (const float*)d_in[7];
    float* outp = (float*)d_out;

    _Float16* wf = (_Float16*)d_ws;   // 425984 bytes
    prep_frags_all<<<dim3(416), dim3(256), 0, stream>>>(W1, W2, W3, wf);
    scl_mfma<<<dim3(512), dim3(512), 0, stream>>>(cond, act, b1, b2, b3, wf, outp);
}